// Round 1
// baseline (78.843 us; speedup 1.0000x reference)
//
#include <hip/hip_runtime.h>

#define BS 512
#define MARGIN 0.5f

__device__ inline float waveReduceSum(float v) {
#pragma unroll
    for (int o = 32; o > 0; o >>= 1) v += __shfl_down(v, o, 64);
    return v;
}
__device__ inline unsigned int waveReduceSumU(unsigned int v) {
#pragma unroll
    for (int o = 32; o > 0; o >>= 1) v += __shfl_down(v, o, 64);
    return v;
}

// Kernel A: row L2-normalize; write p and sq = sum(p*p) per row.
__global__ __launch_bounds__(256) void knorm(const float* __restrict__ pred,
                                             float* __restrict__ p,
                                             float* __restrict__ sq) {
    const int i = blockIdx.x;
    const int tid = threadIdx.x;
    __shared__ float sbuf[4];
    const float a0 = pred[i * BS + tid];
    const float a1 = pred[i * BS + tid + 256];
    float ss = a0 * a0 + a1 * a1;
    float w = waveReduceSum(ss);
    const int lane = tid & 63, wid = tid >> 6;
    if (lane == 0) sbuf[wid] = w;
    __syncthreads();
    const float tot = sbuf[0] + sbuf[1] + sbuf[2] + sbuf[3];
    const float m = fmaxf(sqrtf(tot), 1e-10f);
    const float p0 = a0 / m, p1 = a1 / m;
    p[i * BS + tid] = p0;
    p[i * BS + tid + 256] = p1;
    float ss2 = p0 * p0 + p1 * p1;
    __syncthreads();  // protect sbuf reuse
    float w2 = waveReduceSum(ss2);
    if (lane == 0) sbuf[wid] = w2;
    __syncthreads();
    if (tid == 0) sq[i] = sbuf[0] + sbuf[1] + sbuf[2] + sbuf[3];
}

// Kernel B: dist[i][j] = sqrt(max(sq_i + sq_j - 2*dot(p_i,p_j), 0)). 16x16 LDS tiles.
#define TS 16
__global__ __launch_bounds__(256) void kdist(const float* __restrict__ p,
                                             const float* __restrict__ sq,
                                             float* __restrict__ dist) {
    __shared__ float As[TS][TS + 1];
    __shared__ float Bs[TS][TS + 1];
    const int tx = threadIdx.x & 15;
    const int ty = threadIdx.x >> 4;
    const int row = blockIdx.y * TS + ty;
    const int col = blockIdx.x * TS + tx;
    float acc = 0.f;
    for (int k0 = 0; k0 < BS; k0 += TS) {
        As[ty][tx] = p[row * BS + k0 + tx];
        Bs[ty][tx] = p[(blockIdx.x * TS + ty) * BS + k0 + tx];
        __syncthreads();
#pragma unroll
        for (int k = 0; k < TS; ++k) acc += As[ty][k] * Bs[tx][k];
        __syncthreads();
    }
    float d2 = -2.0f * acc + sq[row] + sq[col];
    d2 = fmaxf(d2, 0.f);
    dist[row * BS + col] = sqrtf(d2);
}

// Kernel C: per-anchor i (target==1): sum/count of max(d[i,j]-d[i,k]+margin,0)
// over j in P\{i}, k in N. Partials per block, no atomics.
__global__ __launch_bounds__(256) void ktriplet(const float* __restrict__ dist,
                                                const int* __restrict__ target,
                                                float* __restrict__ psum,
                                                unsigned int* __restrict__ pcnt) {
    const int i = blockIdx.x;
    const int tid = threadIdx.x;
    __shared__ float drow[BS];
    __shared__ int tgt[BS];
    __shared__ float sbuf[4];
    __shared__ unsigned int cbuf[4];
    for (int t = tid; t < BS; t += 256) {
        drow[t] = dist[i * BS + t];
        tgt[t] = target[t];
    }
    __syncthreads();
    float sum = 0.f;
    unsigned int cnt = 0;
    const float dk0 = drow[tid];
    const float dk1 = drow[tid + 256];
    const bool n0 = (tgt[tid] == 0);
    const bool n1 = (tgt[tid + 256] == 0);
    if (tgt[i] == 1) {
        for (int j = 0; j < BS; ++j) {
            if (tgt[j] != 1 || j == i) continue;  // uniform branch
            const float thr = drow[j] + MARGIN;
            if (n0) {
                float v = thr - dk0;
                if (v > 0.f) { sum += v; cnt++; }
            }
            if (n1) {
                float v = thr - dk1;
                if (v > 0.f) { sum += v; cnt++; }
            }
        }
    }
    float wsm = waveReduceSum(sum);
    unsigned int wc = waveReduceSumU(cnt);
    const int lane = tid & 63, wid = tid >> 6;
    if (lane == 0) { sbuf[wid] = wsm; cbuf[wid] = wc; }
    __syncthreads();
    if (tid == 0) {
        psum[i] = sbuf[0] + sbuf[1] + sbuf[2] + sbuf[3];
        pcnt[i] = cbuf[0] + cbuf[1] + cbuf[2] + cbuf[3];
    }
}

// Kernel D: final reduce + divide.
__global__ __launch_bounds__(256) void kfinal(const float* __restrict__ psum,
                                              const unsigned int* __restrict__ pcnt,
                                              float* __restrict__ out) {
    const int tid = threadIdx.x;
    __shared__ float sbuf[4];
    __shared__ unsigned int cbuf[4];
    float s = psum[tid] + psum[tid + 256];
    unsigned int c = pcnt[tid] + pcnt[tid + 256];
    float wsm = waveReduceSum(s);
    unsigned int wc = waveReduceSumU(c);
    const int lane = tid & 63, wid = tid >> 6;
    if (lane == 0) { sbuf[wid] = wsm; cbuf[wid] = wc; }
    __syncthreads();
    if (tid == 0) {
        float total = sbuf[0] + sbuf[1] + sbuf[2] + sbuf[3];
        unsigned int cn = cbuf[0] + cbuf[1] + cbuf[2] + cbuf[3];
        out[0] = total / ((float)cn + 1e-7f);
    }
}

extern "C" void kernel_launch(void* const* d_in, const int* in_sizes, int n_in,
                              void* d_out, int out_size, void* d_ws, size_t ws_size,
                              hipStream_t stream) {
    const float* pred = (const float*)d_in[0];
    const int* target = (const int*)d_in[1];
    float* out = (float*)d_out;
    float* ws = (float*)d_ws;

    float* p = ws;                                        // 512*512
    float* dist = ws + 262144;                            // 512*512
    float* sq = ws + 524288;                              // 512
    float* psum = ws + 524800;                            // 512
    unsigned int* pcnt = (unsigned int*)(ws + 525312);    // 512

    knorm<<<512, 256, 0, stream>>>(pred, p, sq);
    dim3 gb(32, 32);
    kdist<<<gb, 256, 0, stream>>>(p, sq, dist);
    ktriplet<<<512, 256, 0, stream>>>(dist, target, psum, pcnt);
    kfinal<<<1, 256, 0, stream>>>(psum, pcnt, out);
}

// Round 2
// 55.514 us; speedup vs baseline: 1.4203x; 1.4203x over previous
//
#include <hip/hip_runtime.h>

#define BS 512
#define MARGIN 0.5f

__device__ inline float waveReduceSum(float v) {
#pragma unroll
    for (int o = 32; o > 0; o >>= 1) v += __shfl_down(v, o, 64);
    return v;
}

// Kernel A: row L2-normalize; write p and sq = sum(p*p) per row.
__global__ __launch_bounds__(256) void knorm(const float* __restrict__ pred,
                                             float* __restrict__ p,
                                             float* __restrict__ sq) {
    const int i = blockIdx.x;
    const int tid = threadIdx.x;
    __shared__ float sbuf[4];
    const float a0 = pred[i * BS + tid];
    const float a1 = pred[i * BS + tid + 256];
    float ss = a0 * a0 + a1 * a1;
    float w = waveReduceSum(ss);
    const int lane = tid & 63, wid = tid >> 6;
    if (lane == 0) sbuf[wid] = w;
    __syncthreads();
    const float tot = sbuf[0] + sbuf[1] + sbuf[2] + sbuf[3];
    const float m = fmaxf(sqrtf(tot), 1e-10f);
    const float p0 = a0 / m, p1 = a1 / m;
    p[i * BS + tid] = p0;
    p[i * BS + tid + 256] = p1;
    float ss2 = p0 * p0 + p1 * p1;
    __syncthreads();  // protect sbuf reuse
    float w2 = waveReduceSum(ss2);
    if (lane == 0) sbuf[wid] = w2;
    __syncthreads();
    if (tid == 0) sq[i] = sbuf[0] + sbuf[1] + sbuf[2] + sbuf[3];
}

// Kernel B: dist[i][j] = sqrt(max(sq_i + sq_j - 2*dot(p_i,p_j), 0)). 16x16 LDS tiles.
#define TS 16
__global__ __launch_bounds__(256) void kdist(const float* __restrict__ p,
                                             const float* __restrict__ sq,
                                             float* __restrict__ dist) {
    __shared__ float As[TS][TS + 1];
    __shared__ float Bs[TS][TS + 1];
    const int tx = threadIdx.x & 15;
    const int ty = threadIdx.x >> 4;
    const int row = blockIdx.y * TS + ty;
    const int col = blockIdx.x * TS + tx;
    float acc = 0.f;
    for (int k0 = 0; k0 < BS; k0 += TS) {
        As[ty][tx] = p[row * BS + k0 + tx];
        Bs[ty][tx] = p[(blockIdx.x * TS + ty) * BS + k0 + tx];
        __syncthreads();
#pragma unroll
        for (int k = 0; k < TS; ++k) acc += As[ty][k] * Bs[tx][k];
        __syncthreads();
    }
    float d2 = -2.0f * acc + sq[row] + sq[col];
    d2 = fmaxf(d2, 0.f);
    dist[row * BS + col] = sqrtf(d2);
}

// Kernel C: per-anchor i (target==1), j-half per blockIdx.y:
// partial sum/count of max(d[i,j]-d[i,k]+margin,0) over j in P\{i} (within half), k in N.
// Branchless inner loop, unrolled, float count (exact: <= 2^17 per block).
__global__ __launch_bounds__(256) void ktriplet(const float* __restrict__ dist,
                                                const int* __restrict__ target,
                                                float* __restrict__ psum,
                                                float* __restrict__ pcnt) {
    const int i = blockIdx.x;
    const int half = blockIdx.y;
    const int tid = threadIdx.x;
    __shared__ float drow[BS];
    __shared__ float maskP[BS];
    __shared__ float sbuf[4];
    __shared__ float cbuf[4];
    const int out_idx = i * 2 + half;

    // stage dist row + positive-mask (j != i) into LDS
    for (int t = tid; t < BS; t += 256) {
        drow[t] = dist[i * BS + t];
        maskP[t] = (target[t] == 1 && t != i) ? 1.0f : 0.0f;
    }
    __syncthreads();

    float sum0 = 0.f, sum1 = 0.f, cnt0 = 0.f, cnt1 = 0.f;
    const float dk0 = drow[tid];
    const float dk1 = drow[tid + 256];
    const float nk0 = (target[tid] == 0) ? 1.0f : 0.0f;
    const float nk1 = (target[tid + 256] == 0) ? 1.0f : 0.0f;

    if (target[i] == 1) {
        const int j0 = half * 256;
#pragma unroll 8
        for (int j = j0; j < j0 + 256; ++j) {
            const float pm = maskP[j];
            const float am = drow[j] + MARGIN;
            const float v0 = am - dk0;
            const float v1 = am - dk1;
            sum0 += fmaxf(v0, 0.f) * pm;
            sum1 += fmaxf(v1, 0.f) * pm;
            cnt0 += (v0 > 0.f) ? pm : 0.f;
            cnt1 += (v1 > 0.f) ? pm : 0.f;
        }
    }
    float sum = sum0 * nk0 + sum1 * nk1;
    float cnt = cnt0 * nk0 + cnt1 * nk1;

    float wsm = waveReduceSum(sum);
    float wc = waveReduceSum(cnt);
    const int lane = tid & 63, wid = tid >> 6;
    if (lane == 0) { sbuf[wid] = wsm; cbuf[wid] = wc; }
    __syncthreads();
    if (tid == 0) {
        psum[out_idx] = sbuf[0] + sbuf[1] + sbuf[2] + sbuf[3];
        pcnt[out_idx] = cbuf[0] + cbuf[1] + cbuf[2] + cbuf[3];
    }
}

// Kernel D: final reduce over 1024 partials + divide.
__global__ __launch_bounds__(256) void kfinal(const float* __restrict__ psum,
                                              const float* __restrict__ pcnt,
                                              float* __restrict__ out) {
    const int tid = threadIdx.x;
    __shared__ float sbuf[4];
    __shared__ float cbuf[4];
    float s = psum[tid] + psum[tid + 256] + psum[tid + 512] + psum[tid + 768];
    float c = pcnt[tid] + pcnt[tid + 256] + pcnt[tid + 512] + pcnt[tid + 768];
    float wsm = waveReduceSum(s);
    float wc = waveReduceSum(c);
    const int lane = tid & 63, wid = tid >> 6;
    if (lane == 0) { sbuf[wid] = wsm; cbuf[wid] = wc; }
    __syncthreads();
    if (tid == 0) {
        float total = sbuf[0] + sbuf[1] + sbuf[2] + sbuf[3];
        float cn = cbuf[0] + cbuf[1] + cbuf[2] + cbuf[3];
        out[0] = total / (cn + 1e-7f);
    }
}

extern "C" void kernel_launch(void* const* d_in, const int* in_sizes, int n_in,
                              void* d_out, int out_size, void* d_ws, size_t ws_size,
                              hipStream_t stream) {
    const float* pred = (const float*)d_in[0];
    const int* target = (const int*)d_in[1];
    float* out = (float*)d_out;
    float* ws = (float*)d_ws;

    float* p = ws;                                 // 512*512
    float* dist = ws + 262144;                     // 512*512
    float* sq = ws + 524288;                       // 512
    float* psum = ws + 524800;                     // 1024
    float* pcnt = ws + 525824;                     // 1024

    knorm<<<512, 256, 0, stream>>>(pred, p, sq);
    dim3 gb(32, 32);
    kdist<<<gb, 256, 0, stream>>>(p, sq, dist);
    dim3 gt(512, 2);
    ktriplet<<<gt, 256, 0, stream>>>(dist, target, psum, pcnt);
    kfinal<<<1, 256, 0, stream>>>(psum, pcnt, out);
}